// Round 10
// baseline (695.739 us; speedup 1.0000x reference)
//
#include <hip/hip_runtime.h>
#include <hip/hip_bf16.h>
#include <math.h>

typedef __bf16 bf16_t;
typedef float f32x4 __attribute__((ext_vector_type(4)));
typedef bf16_t bf16x8 __attribute__((ext_vector_type(8)));
typedef unsigned int u32;
typedef u32 u32x2 __attribute__((ext_vector_type(2)));
typedef u32 u32x4 __attribute__((ext_vector_type(4)));
typedef unsigned short u16x4 __attribute__((ext_vector_type(4)));

#define GLD_LDS16(gp, lp) __builtin_amdgcn_global_load_lds( \
    (const __attribute__((address_space(1))) void*)(gp), \
    (__attribute__((address_space(3))) void*)(lp), 16, 0, 0)

static __device__ __forceinline__ unsigned short f2b(float f) {
  union { bf16_t b; unsigned short s; } u; u.b = (bf16_t)f; return u.s;
}
static __device__ __forceinline__ float b2f(unsigned short s) {
  union { unsigned int i; float f; } u; u.i = ((unsigned)s) << 16; return u.f;
}
static __device__ __forceinline__ u32 packbf(float a, float b) {
  return (u32)f2b(a) | ((u32)f2b(b) << 16);
}

// ---------------- weight prep: jobs 0..3 transpose+cast, jobs 4..6 plain cast ----------------
struct TC7 { const float* src[7]; bf16_t* dst[7]; };
__global__ __launch_bounds__(256) void tcast7_kernel(TC7 tc) {
  int job = blockIdx.x >> 10;
  int idx = (blockIdx.x & 1023) * 256 + threadIdx.x;
  if (job < 4) {
    int n = idx >> 9, k = idx & 511;
    tc.dst[job][idx] = (bf16_t)tc.src[job][k * 512 + n];
  } else {
    tc.dst[job][idx] = (bf16_t)tc.src[job][idx];
  }
}

// ---------------- cc[n] = sum_d db2[d]*gw1[d][n] + gb1[n] ----------------
__global__ __launch_bounds__(256) void cc_kernel(const float* __restrict__ db2, const float* __restrict__ gw1,
                                                 const float* __restrict__ gb1, float* __restrict__ cc) {
  int n = blockIdx.x * 256 + threadIdx.x;
  float s = gb1[n];
  for (int d = 0; d < 512; ++d) s = fmaf(db2[d], gw1[d * 512 + n], s);
  cc[n] = s;
}

// ---------------- KNN: one WAVE per query; per-lane u64 keys in registers ----------------
__global__ __launch_bounds__(256) void knn_kernel(const float* __restrict__ xyz, int* __restrict__ knn) {
  __shared__ float sx[2048], sy[2048], sz[2048], sq[2048];
  int tid = threadIdx.x;
  int lane = tid & 63, wave = tid >> 6;
  int gq = blockIdx.x * 4 + wave;
  int b  = gq >> 11;
  int base = b << 11;
  for (int p = tid; p < 2048; p += 256) {
    float x = xyz[(base + p) * 3 + 0];
    float y = xyz[(base + p) * 3 + 1];
    float z = xyz[(base + p) * 3 + 2];
    sx[p] = x; sy[p] = y; sz[p] = z;
    sq[p] = __fadd_rn(__fadd_rn(__fmul_rn(x, x), __fmul_rn(y, y)), __fmul_rn(z, z));
  }
  __syncthreads();
  int iq = gq & 2047;
  float qx = sx[iq], qy = sy[iq], qz = sz[iq], sqi = sq[iq];

  unsigned long long key[32];
  #pragma unroll
  for (int j = 0; j < 32; ++j) {
    int p = lane + j * 64;
    float d = __fmul_rn(sx[p], qx);
    d = fmaf(sy[p], qy, d);
    d = fmaf(sz[p], qz, d);
    float dist = __fsub_rn(__fadd_rn(sqi, sq[p]), __fmul_rn(2.0f, d));
    unsigned int bits = __float_as_uint(dist);
    unsigned int sk = bits ^ (unsigned int)(((int)bits >> 31) | 0x80000000);
    key[j] = ((unsigned long long)sk << 32) | (unsigned int)p;
  }

  int r = 0;
  #pragma unroll 1
  for (int s = 0; s < 16; ++s) {
    unsigned long long m = key[0];
    #pragma unroll
    for (int j = 1; j < 32; ++j) m = (key[j] < m) ? key[j] : m;
    #pragma unroll
    for (int off = 32; off > 0; off >>= 1) {
      unsigned long long o = (unsigned long long)__shfl_xor((long long)m, off);
      if (o < m) m = o;
    }
    if (lane == s) r = base + (int)(m & 0xFFFFFFFFu);
    #pragma unroll
    for (int j = 0; j < 32; ++j) key[j] = (key[j] == m) ? ~0ULL : key[j];
  }
  if (lane < 16) knn[gq * 16 + lane] = r;
}

// ---------------- x = points @ fc1_w + fc1_b -> bf16 [4096][512] ----------------
__global__ __launch_bounds__(256) void xfeat_kernel(const float* __restrict__ points, const float* __restrict__ fc1_w,
                                                    const float* __restrict__ fc1_b, bf16_t* __restrict__ xb) {
  __shared__ float p[32];
  int m = blockIdx.x, tid = threadIdx.x;
  if (tid < 32) p[tid] = points[m * 32 + tid];
  __syncthreads();
  for (int c = tid; c < 512; c += 256) {
    float a = fc1_b[c];
    #pragma unroll
    for (int kk = 0; kk < 32; ++kk) a = fmaf(p[kk], fc1_w[kk * 512 + c], a);
    xb[m * 512 + c] = (bf16_t)a;
  }
}

// ---------------- res = res_mid @ fc2_w + fc2_b + points -> d_out[0:131072] ----------------
__global__ __launch_bounds__(256) void final_kernel(const float* __restrict__ res_mid, const float* __restrict__ fc2_w,
                                                    const float* __restrict__ fc2_b, const float* __restrict__ points,
                                                    float* __restrict__ out) {
  int oid = blockIdx.x * 256 + threadIdx.x;
  int m = oid >> 5, c = oid & 31;
  float a = fc2_b[c];
  const float* rm = res_mid + m * 512;
  for (int kk = 0; kk < 512; ++kk) a = fmaf(rm[kk], fc2_w[kk * 32 + c], a);
  out[oid] = a + points[oid];
}

// ---------------- small-GEMM engine (proven R9): BKT=32, counted-vmcnt dbuf ----------------
// EPI: 4 = transposed bf16 store w/ job-select (weight products); 6 = part-major bf16 (v|qg|kg)
struct GP {
  const bf16_t* A; const bf16_t* Bt; bf16_t* Cb; int ldc;
  const bf16_t* Aj[3]; bf16_t* Cbj[3];
};

template <int EPI>
__global__ __launch_bounds__(256) void gemm_kernel(GP gp) {
  __shared__ bf16_t Alds[2 * 128 * 32];
  __shared__ bf16_t Blds[2 * 128 * 32];
  int tid  = threadIdx.x;
  int lane = tid & 63, wave = tid >> 6;
  int wr = wave >> 1, wc = wave & 1;
  int lr = lane & 15, lg = lane >> 4;

  int gx = gridDim.x;
  int nwg = gx * gridDim.y;
  int orig = blockIdx.y * gx + blockIdx.x;
  int cpx = nwg >> 3;
  int swz = (orig & 7) * cpx + (orig >> 3);
  int bx = swz % gx;
  int by = swz / gx;
  int n0 = bx * 128;
  int m0 = ((EPI == 4) ? (by & 3) : by) * 128;
  const bf16_t* Aptr = (EPI == 4) ? gp.Aj[by >> 2] : gp.A;

  f32x4 acc[4][4];
  #pragma unroll
  for (int i = 0; i < 4; ++i)
    #pragma unroll
    for (int j = 0; j < 4; ++j) acc[i][j] = (f32x4){0.f, 0.f, 0.f, 0.f};

  int rS2 = tid >> 2;
  int swb = (rS2 >> 1) & 3;
  int scS = (((tid & 3) ^ swb) << 3);

  auto stageA = [&](int t, int buf) {
    int k0 = t * 32;
    GLD_LDS16(Aptr + (size_t)(m0 + rS2) * 512 + k0 + scS,       Alds + buf * 4096 + tid * 8);
    GLD_LDS16(Aptr + (size_t)(m0 + 64 + rS2) * 512 + k0 + scS,  Alds + buf * 4096 + 2048 + tid * 8);
  };
  auto stageB = [&](int t, int buf) {
    int k0 = t * 32;
    GLD_LDS16(gp.Bt + (size_t)(n0 + rS2) * 512 + k0 + scS,       Blds + buf * 4096 + tid * 8);
    GLD_LDS16(gp.Bt + (size_t)(n0 + 64 + rS2) * 512 + k0 + scS,  Blds + buf * 4096 + 2048 + tid * 8);
  };

  stageA(0, 0);
  stageB(0, 0);

  #pragma unroll 1
  for (int t = 0; t < 16; ++t) {
    int cur = t & 1;
    if (t + 1 < 16) {
      stageA(t + 1, cur ^ 1);
      stageB(t + 1, cur ^ 1);
      asm volatile("s_waitcnt vmcnt(4)" ::: "memory");
    } else {
      asm volatile("s_waitcnt vmcnt(0)" ::: "memory");
    }
    __builtin_amdgcn_s_barrier();
    const bf16_t* Ab = Alds + cur * 4096;
    const bf16_t* Bb = Blds + cur * 4096;
    bf16x8 af[4], bfr[4];
    #pragma unroll
    for (int mi = 0; mi < 4; ++mi) {
      int rr = wr * 64 + mi * 16 + lr;
      af[mi] = *(const bf16x8*)(&Ab[rr * 32 + ((lg ^ ((rr >> 1) & 3)) << 3)]);
    }
    #pragma unroll
    for (int nj = 0; nj < 4; ++nj) {
      int rr = wc * 64 + nj * 16 + lr;
      bfr[nj] = *(const bf16x8*)(&Bb[rr * 32 + ((lg ^ ((rr >> 1) & 3)) << 3)]);
    }
    #pragma unroll
    for (int mi = 0; mi < 4; ++mi)
      #pragma unroll
      for (int nj = 0; nj < 4; ++nj)
        acc[mi][nj] = __builtin_amdgcn_mfma_f32_16x16x32_bf16(af[mi], bfr[nj], acc[mi][nj], 0, 0, 0);
    __builtin_amdgcn_s_barrier();
  }

  if (EPI == 4) {
    bf16_t* CbT = gp.Cbj[by >> 2];
    #pragma unroll
    for (int mi = 0; mi < 4; ++mi)
      #pragma unroll
      for (int nj = 0; nj < 4; ++nj) {
        int col = n0 + wc * 64 + nj * 16 + lr;
        #pragma unroll
        for (int r = 0; r < 4; ++r) {
          int row = m0 + wr * 64 + mi * 16 + lg * 4 + r;
          CbT[(size_t)col * 512 + row] = (bf16_t)acc[mi][nj][r];
        }
      }
  } else {
    #pragma unroll
    for (int mi = 0; mi < 4; ++mi)
      #pragma unroll
      for (int nj = 0; nj < 4; ++nj) {
        int col = n0 + wc * 64 + nj * 16 + lr;
        int part = col >> 9, c = col & 511;
        #pragma unroll
        for (int r = 0; r < 4; ++r) {
          int row = m0 + wr * 64 + mi * 16 + lg * 4 + r;
          gp.Cb[((size_t)part * 4096 + row) * 512 + c] = (bf16_t)acc[mi][nj][r];
        }
      }
  }
}

// ---------------- FUSED: h1(regs) -> pe(regs) + h2'(regs, transposed) -> a2 -> softmax/attn/res_mid ----
// 4 waves, 64 rows/block, wave w <-> group g. pe/h2 NEVER touch HBM.
// h2' via swapped mfma(WpT_frag, h1_frag): lane holds h2[row=lane&15][col=16T+lg*4+r] -> A-frag rows
// already lane-aligned; col regroup via 16B/lane per-step LDS bounce (per-wave slice, no barriers).
struct FP {
  const float* xyz; const int* knn;
  const float* dw1; const float* db1; const float* db2; const float* cc; const float* gb2;
  const bf16_t* WpT; const bf16_t* dw2T; const bf16_t* gw2T;
  const bf16_t* vqkg;
  float* attn; float* res_mid;
};

__global__ __launch_bounds__(256, 2) void fused_kernel(FP fp) {
  __shared__ float  wl[3584];          // dw1[0:1536], db1@1536, cc@2048, db2@2560, gb2@3072
  __shared__ bf16_t Bst[2 * 128 * 32]; // B staging dbuf
  __shared__ u32    bounce[4 * 256];   // per-wave 1KB bounce

  int tid = threadIdx.x, lane = tid & 63, w = tid >> 6;
  int lr = lane & 15, lg = lane >> 4;

  int nwg = gridDim.x, orig = blockIdx.x, cpx = nwg >> 3;
  int bid = (orig & 7) * cpx + (orig >> 3);
  int m0 = bid * 64;
  int g  = (m0 >> 4) + w;
  int myrow = m0 + w * 16 + lr;
  int j_lane = fp.knn[myrow];
  float dx = fp.xyz[g * 3 + 0] - fp.xyz[j_lane * 3 + 0];
  float dy = fp.xyz[g * 3 + 1] - fp.xyz[j_lane * 3 + 1];
  float dz = fp.xyz[g * 3 + 2] - fp.xyz[j_lane * 3 + 2];

  for (int c = tid; c < 1536; c += 256) wl[c] = fp.dw1[c];
  for (int c = tid; c < 512; c += 256) {
    wl[1536 + c] = fp.db1[c];
    wl[2048 + c] = fp.cc[c];
    wl[2560 + c] = fp.db2[c];
    wl[3072 + c] = fp.gb2[c];
  }
  __syncthreads();

  // h1 fragment for k-step st: element u <-> h1[row=lr][k=32*st+lg*8+u]  (A- and B-frag compatible)
  auto h1frag = [&](int st) -> bf16x8 {
    int c = st * 32 + lg * 8;
    f32x4 w0a = *(const f32x4*)&wl[c],        w0b = *(const f32x4*)&wl[c + 4];
    f32x4 w1a = *(const f32x4*)&wl[512 + c],  w1b = *(const f32x4*)&wl[512 + c + 4];
    f32x4 w2a = *(const f32x4*)&wl[1024 + c], w2b = *(const f32x4*)&wl[1024 + c + 4];
    f32x4 ba  = *(const f32x4*)&wl[1536 + c], bb = *(const f32x4*)&wl[1536 + c + 4];
    bf16x8 o;
    #pragma unroll
    for (int u = 0; u < 4; ++u) {
      float h = fmaf(dz, w2a[u], fmaf(dy, w1a[u], dx * w0a[u])) + ba[u];
      o[u] = (bf16_t)fmaxf(h, 0.0f);
    }
    #pragma unroll
    for (int u = 0; u < 4; ++u) {
      float h = fmaf(dz, w2b[u], fmaf(dy, w1b[u], dx * w0b[u])) + bb[u];
      o[4 + u] = (bf16_t)fmaxf(h, 0.0f);
    }
    return o;
  };

  int rS2 = tid >> 2;
  int scS = (((tid & 3) ^ ((rS2 >> 1) & 3)) << 3);
  auto stage = [&](const bf16_t* Bt, int base, int st, int buf) {
    GLD_LDS16(Bt + (size_t)(base + rS2) * 512 + st * 32 + scS,      Bst + buf * 4096 + tid * 8);
    GLD_LDS16(Bt + (size_t)(base + 64 + rS2) * 512 + st * 32 + scS, Bst + buf * 4096 + 2048 + tid * 8);
  };
  auto bfrag = [&](int buf, int tt) -> bf16x8 {
    int rr = tt * 16 + lr;
    return *(const bf16x8*)(&Bst[buf * 4096 + rr * 32 + ((lg ^ ((rr >> 1) & 3)) << 3)]);
  };

  u32 h2pk[32][2];
  u32 pepk[32][2];

  // ======== PHASE 1: h2' (transposed) = relu(Wp^T-swap + cc + qg - kg) ========
  #pragma unroll
  for (int mc = 0; mc < 4; ++mc) {
    f32x4 acc1[8];
    #pragma unroll
    for (int i = 0; i < 8; ++i) acc1[i] = (f32x4){0.f, 0.f, 0.f, 0.f};
    stage(fp.WpT, mc * 128, 0, 0);
    #pragma unroll 1
    for (int st = 0; st < 16; ++st) {
      if (st < 15) {
        stage(fp.WpT, mc * 128, st + 1, (st & 1) ^ 1);
        asm volatile("s_waitcnt vmcnt(2)" ::: "memory");
      } else {
        asm volatile("s_waitcnt vmcnt(0)" ::: "memory");
      }
      __builtin_amdgcn_s_barrier();
      bf16x8 bh = h1frag(st);
      #pragma unroll
      for (int tt = 0; tt < 8; ++tt)
        acc1[tt] = __builtin_amdgcn_mfma_f32_16x16x32_bf16(bfrag(st & 1, tt), bh, acc1[tt], 0, 0, 0);
      __builtin_amdgcn_s_barrier();
    }
    #pragma unroll
    for (int tt = 0; tt < 8; ++tt) {
      int c0 = mc * 128 + tt * 16 + lg * 4;
      u16x4 kg4 = *(const u16x4*)((const unsigned short*)fp.vqkg + ((size_t)2 * 4096 + j_lane) * 512 + c0);
      u16x4 qg4 = *(const u16x4*)((const unsigned short*)fp.vqkg + ((size_t)4096 + g) * 512 + c0);
      f32x4 cc4 = *(const f32x4*)&wl[2048 + c0];
      float hv[4];
      #pragma unroll
      for (int r = 0; r < 4; ++r)
        hv[r] = fmaxf(acc1[tt][r] + cc4[r] + b2f(qg4[r]) - b2f(kg4[r]), 0.0f);
      h2pk[mc * 8 + tt][0] = packbf(hv[0], hv[1]);
      h2pk[mc * 8 + tt][1] = packbf(hv[2], hv[3]);
    }
  }

  // ======== PHASE 2: pe = h1 @ dw2T + db2 (registers only) ========
  #pragma unroll
  for (int nc = 0; nc < 4; ++nc) {
    f32x4 acc2[8];
    #pragma unroll
    for (int i = 0; i < 8; ++i) acc2[i] = (f32x4){0.f, 0.f, 0.f, 0.f};
    stage(fp.dw2T, nc * 128, 0, 0);
    #pragma unroll 1
    for (int st = 0; st < 16; ++st) {
      if (st < 15) {
        stage(fp.dw2T, nc * 128, st + 1, (st & 1) ^ 1);
        asm volatile("s_waitcnt vmcnt(2)" ::: "memory");
      } else {
        asm volatile("s_waitcnt vmcnt(0)" ::: "memory");
      }
      __builtin_amdgcn_s_barrier();
      bf16x8 ah = h1frag(st);
      #pragma unroll
      for (int tt = 0; tt < 8; ++tt)
        acc2[tt] = __builtin_amdgcn_mfma_f32_16x16x32_bf16(ah, bfrag(st & 1, tt), acc2[tt], 0, 0, 0);
      __builtin_amdgcn_s_barrier();
    }
    #pragma unroll
    for (int tt = 0; tt < 8; ++tt) {
      int col = nc * 128 + tt * 16 + lr;
      float d2 = wl[2560 + col];
      pepk[nc * 8 + tt][0] = packbf(acc2[tt][0] + d2, acc2[tt][1] + d2);
      pepk[nc * 8 + tt][1] = packbf(acc2[tt][2] + d2, acc2[tt][3] + d2);
    }
  }

  // ======== PHASE 3: a2 = h2 @ gw2T + gb2; softmax; attn; res_mid ========
  u32* bw = &bounce[w * 256];
  int wrOff = lane * 4;
  int rdA = (lr + ((lg & 1) << 5)) * 4 + (lg >> 1) * 2;
  int rdB = rdA + 64;
  int jr[4];
  #pragma unroll
  for (int r = 0; r < 4; ++r) jr[r] = __shfl(j_lane, lg * 4 + r);

  const float scale = 22.62741699796952f;   // float(np.sqrt(512))

  #pragma unroll
  for (int nc = 0; nc < 4; ++nc) {
    f32x4 acc3[8];
    #pragma unroll
    for (int i = 0; i < 8; ++i) acc3[i] = (f32x4){0.f, 0.f, 0.f, 0.f};
    stage(fp.gw2T, nc * 128, 0, 0);

#define P3STEP(ST) { \
    if ((ST) < 15) { stage(fp.gw2T, nc * 128, (ST) + 1, ((ST) & 1) ^ 1); \
                     asm volatile("s_waitcnt vmcnt(2)" ::: "memory"); } \
    else           { asm volatile("s_waitcnt vmcnt(0)" ::: "memory"); } \
    __builtin_amdgcn_s_barrier(); \
    *(u32x4*)(bw + wrOff) = (u32x4){h2pk[2*(ST)][0], h2pk[2*(ST)][1], h2pk[2*(ST)+1][0], h2pk[2*(ST)+1][1]}; \
    asm volatile("s_waitcnt lgkmcnt(0)" ::: "memory"); \
    union { bf16x8 v; u32x2 h[2]; } afu; \
    afu.h[0] = *(const u32x2*)(bw + rdA); \
    afu.h[1] = *(const u32x2*)(bw + rdB); \
    _Pragma("unroll") \
    for (int tt = 0; tt < 8; ++tt) \
      acc3[tt] = __builtin_amdgcn_mfma_f32_16x16x32_bf16(afu.v, bfrag((ST) & 1, tt), acc3[tt], 0, 0, 0); \
    __builtin_amdgcn_s_barrier(); }

    P3STEP(0)  P3STEP(1)  P3STEP(2)  P3STEP(3)
    P3STEP(4)  P3STEP(5)  P3STEP(6)  P3STEP(7)
    P3STEP(8)  P3STEP(9)  P3STEP(10) P3STEP(11)
    P3STEP(12) P3STEP(13) P3STEP(14) P3STEP(15)
#undef P3STEP

    #pragma unroll
    for (int tt = 0; tt < 8; ++tt) {
      int col = nc * 128 + tt * 16 + lr;
      float gb2v = wl[3072 + col];
      float sv[4];
      float mx = -INFINITY;
      #pragma unroll
      for (int r = 0; r < 4; ++r) {
        sv[r] = (acc3[tt][r] + gb2v) / scale;
        mx = fmaxf(mx, sv[r]);
      }
      mx = fmaxf(mx, __shfl_xor(mx, 16));
      mx = fmaxf(mx, __shfl_xor(mx, 32));
      float e[4], sum = 0.f;
      #pragma unroll
      for (int r = 0; r < 4; ++r) { e[r] = expf(sv[r] - mx); sum += e[r]; }
      sum += __shfl_xor(sum, 16);
      sum += __shfl_xor(sum, 32);
      float part = 0.f;
      #pragma unroll
      for (int r = 0; r < 4; ++r) {
        int row = g * 16 + lg * 4 + r;
        float at = e[r] / sum;
        float vv = (float)fp.vqkg[(size_t)jr[r] * 512 + col];
        u32 pw = pepk[nc * 8 + tt][r >> 1];
        float pev = b2f((unsigned short)(pw >> (16 * (r & 1))));
        part = fmaf(at, vv + pev, part);
        fp.attn[(size_t)row * 512 + col] = at;
      }
      part += __shfl_xor(part, 16);
      part += __shfl_xor(part, 32);
      if (lg == 0) fp.res_mid[(size_t)g * 512 + col] = part;
    }
  }
}

extern "C" void kernel_launch(void* const* d_in, const int* in_sizes, int n_in,
                              void* d_out, int out_size, void* d_ws, size_t ws_size,
                              hipStream_t stream) {
  const float* xyz    = (const float*)d_in[0];
  const float* points = (const float*)d_in[1];
  const float* fc1_w  = (const float*)d_in[2];
  const float* fc1_b  = (const float*)d_in[3];
  const float* fc2_w  = (const float*)d_in[4];
  const float* fc2_b  = (const float*)d_in[5];
  const float* dw1    = (const float*)d_in[6];
  const float* db1    = (const float*)d_in[7];
  const float* dw2    = (const float*)d_in[8];
  const float* db2    = (const float*)d_in[9];
  const float* gw1    = (const float*)d_in[10];
  const float* gb1    = (const float*)d_in[11];
  const float* gw2    = (const float*)d_in[12];
  const float* gb2    = (const float*)d_in[13];
  const float* wq     = (const float*)d_in[14];
  const float* wk     = (const float*)d_in[15];
  const float* wv     = (const float*)d_in[16];

  float* out = (float*)d_out;
  float* attn = out + 131072;   // [65536][512] f32 attn output

  char* w = (char*)d_ws;
  bf16_t* wBig   = (bf16_t*)w; w += (size_t)1536 * 512 * 2;   // [wv^T | Wqg^T | Wkg^T]
  bf16_t* dw2T   = (bf16_t*)w; w += (size_t)512 * 512 * 2;
  bf16_t* gw1T   = (bf16_t*)w; w += (size_t)512 * 512 * 2;
  bf16_t* gw2T   = (bf16_t*)w; w += (size_t)512 * 512 * 2;
  bf16_t* dw2b   = (bf16_t*)w; w += (size_t)512 * 512 * 2;
  bf16_t* wqb    = (bf16_t*)w; w += (size_t)512 * 512 * 2;
  bf16_t* wkb    = (bf16_t*)w; w += (size_t)512 * 512 * 2;
  bf16_t* WpT    = (bf16_t*)w; w += (size_t)512 * 512 * 2;
  float*  cc     = (float*)w;  w += (size_t)512 * 4;
  int*    knn    = (int*)w;    w += (size_t)65536 * 4;
  bf16_t* xb     = (bf16_t*)w; w += (size_t)4096 * 512 * 2;
  bf16_t* vqkg   = (bf16_t*)w; w += (size_t)3 * 4096 * 512 * 2;  // part-major: v, qg, kg
  float*  res_mid= (float*)w;  w += (size_t)4096 * 512 * 4;

  TC7 tc;
  tc.src[0] = wv;  tc.dst[0] = wBig;           // wv^T
  tc.src[1] = dw2; tc.dst[1] = dw2T;
  tc.src[2] = gw1; tc.dst[2] = gw1T;
  tc.src[3] = gw2; tc.dst[3] = gw2T;
  tc.src[4] = dw2; tc.dst[4] = dw2b;
  tc.src[5] = wq;  tc.dst[5] = wqb;
  tc.src[6] = wk;  tc.dst[6] = wkb;
  tcast7_kernel<<<7168, 256, 0, stream>>>(tc);

  knn_kernel<<<1024, 256, 0, stream>>>(xyz, knn);
  xfeat_kernel<<<4096, 256, 0, stream>>>(points, fc1_w, fc1_b, xb);
  cc_kernel<<<2, 256, 0, stream>>>(db2, gw1, gb1, cc);

  // weight products: {dw2, wq, wk} @ gw1 -> {Wp^T, Wqg^T, Wkg^T} (Bt-format)
  GP gwp{};
  gwp.Bt = gw1T;
  gwp.Aj[0] = dw2b; gwp.Cbj[0] = WpT;
  gwp.Aj[1] = wqb;  gwp.Cbj[1] = wBig + (size_t)512 * 512;
  gwp.Aj[2] = wkb;  gwp.Cbj[2] = wBig + (size_t)2 * 512 * 512;
  gemm_kernel<4><<<dim3(4, 12), 256, 0, stream>>>(gwp);

  // fused projection: x @ [wv | wq@gw1 | wk@gw1] -> part-major {v, qg, kg}
  GP gq{};
  gq.A = xb; gq.Bt = wBig; gq.Cb = vqkg; gq.ldc = 1536;
  gemm_kernel<6><<<dim3(12, 32), 256, 0, stream>>>(gq);

  // FUSED chain: h1 -> pe/h2' (registers) -> a2 -> softmax -> attn + res_mid
  FP fp{};
  fp.xyz = xyz; fp.knn = knn;
  fp.dw1 = dw1; fp.db1 = db1; fp.db2 = db2; fp.cc = cc; fp.gb2 = gb2;
  fp.WpT = WpT; fp.dw2T = dw2T; fp.gw2T = gw2T;
  fp.vqkg = vqkg;
  fp.attn = attn; fp.res_mid = res_mid;
  fused_kernel<<<1024, 256, 0, stream>>>(fp);

  final_kernel<<<512, 256, 0, stream>>>(res_mid, fc2_w, fc2_b, points, out);
}